// Round 1
// baseline (922.674 us; speedup 1.0000x reference)
//
#include <hip/hip_runtime.h>
#include <math.h>

#define NN 100000
#define NE 1600000

// ---------------------------------------------------------------- helpers
__device__ __forceinline__ float4 f4fma(float4 a, float s, float4 w) {
  a.x = fmaf(s, w.x, a.x); a.y = fmaf(s, w.y, a.y);
  a.z = fmaf(s, w.z, a.z); a.w = fmaf(s, w.w, a.w);
  return a;
}

// ---------------------------------------------------------------- CSR build
__global__ void hist_k(const int* __restrict__ dst, int* __restrict__ deg) {
  for (int e = blockIdx.x * blockDim.x + threadIdx.x; e < NE;
       e += gridDim.x * blockDim.x)
    atomicAdd(&deg[dst[e]], 1);
}

// 1024 elements per block (256 thr x 4). Writes inclusive scan into rowp1
// (== row_ptr+1) without block offset; block total into bsum.
__global__ __launch_bounds__(256)
void scan1_k(const int* __restrict__ deg, int* __restrict__ rowp1,
             int* __restrict__ bsum) {
  __shared__ int wsum[4];
  const int t = threadIdx.x;
  const int base = blockIdx.x * 1024;
  const int i0 = base + t * 4;
  int v0 = (i0 + 0 < NN) ? deg[i0 + 0] : 0;
  int v1 = (i0 + 1 < NN) ? deg[i0 + 1] : 0;
  int v2 = (i0 + 2 < NN) ? deg[i0 + 2] : 0;
  int v3 = (i0 + 3 < NN) ? deg[i0 + 3] : 0;
  const int s1 = v0 + v1, s2 = s1 + v2, s3 = s2 + v3;
  const int tsum = s3;
  // wave-inclusive scan of per-thread sums
  const int lane = t & 63;
  int incl = tsum;
  #pragma unroll
  for (int off = 1; off < 64; off <<= 1) {
    int n = __shfl_up(incl, off);
    if (lane >= off) incl += n;
  }
  const int wid = t >> 6;
  if (lane == 63) wsum[wid] = incl;
  __syncthreads();
  int woff = 0;
  for (int w = 0; w < wid; ++w) woff += wsum[w];
  const int texcl = incl - tsum + woff;
  if (i0 + 0 < NN) rowp1[i0 + 0] = texcl + v0;
  if (i0 + 1 < NN) rowp1[i0 + 1] = texcl + s1;
  if (i0 + 2 < NN) rowp1[i0 + 2] = texcl + s2;
  if (i0 + 3 < NN) rowp1[i0 + 3] = texcl + s3;
  if (t == 255) bsum[blockIdx.x] = texcl + tsum;
}

// single block: exclusive scan of block sums (nb <= 128)
__global__ void scan2_k(int* __restrict__ bsum, int nb) {
  __shared__ int sh[128];
  const int t = threadIdx.x;
  const int v = (t < nb) ? bsum[t] : 0;
  sh[t] = v;
  __syncthreads();
  #pragma unroll
  for (int off = 1; off < 128; off <<= 1) {
    int nv = (t >= off) ? sh[t - off] : 0;
    __syncthreads();
    sh[t] += nv;
    __syncthreads();
  }
  if (t < nb) bsum[t] = sh[t] - v;
}

__global__ void scan3_k(int* __restrict__ rowp, const int* __restrict__ bsum) {
  const int i = blockIdx.x * blockDim.x + threadIdx.x;
  if (i == 0) rowp[0] = 0;
  if (i < NN) rowp[i + 1] += bsum[i >> 10];
}

__global__ void fill_k(const int* __restrict__ src, const int* __restrict__ dst,
                       int* __restrict__ cursor, int* __restrict__ cidx) {
  for (int e = blockIdx.x * blockDim.x + threadIdx.x; e < NE;
       e += gridDim.x * blockDim.x) {
    const int d = dst[e];
    const int pos = atomicAdd(&cursor[d], 1);
    cidx[pos] = src[e];
  }
}

// ---------------------------------------------------------------- GEMM x4
// O_m = X @ W_m + b_m  (m = 0..3), DIN = 128 fixed, DOUT in {128, 64}
template <int DOUT>
__global__ __launch_bounds__(256)
void gemm4_k(const float* __restrict__ X, int nrows,
             const float* __restrict__ W0, const float* __restrict__ B0, float* __restrict__ O0,
             const float* __restrict__ W1, const float* __restrict__ B1, float* __restrict__ O1,
             const float* __restrict__ W2, const float* __restrict__ B2, float* __restrict__ O2,
             const float* __restrict__ W3, const float* __restrict__ B3, float* __restrict__ O3) {
  constexpr int DIN = 128;
  constexpr int CG = DOUT / 4;     // col groups (threads along cols)
  constexpr int RG = 256 / CG;     // row groups
  constexpr int ROWS = RG * 4;     // rows per block
  constexpr int XPAD = DIN + 4;    // LDS pad to break bank alignment
  __shared__ float Xs[ROWS][XPAD];
  __shared__ float Wl[64][DOUT];   // half of W (K-split staging)
  const int t = threadIdx.x;
  const int row0 = blockIdx.x * ROWS;
  // stage X tile
  {
    const int nv = ROWS * (DIN / 4);
    for (int i = t; i < nv; i += 256) {
      const int r = i >> 5;        // DIN/4 == 32
      const int c4 = i & 31;
      float4 vv = make_float4(0.f, 0.f, 0.f, 0.f);
      if (row0 + r < nrows) vv = *(const float4*)&X[(size_t)(row0 + r) * DIN + c4 * 4];
      *(float4*)&Xs[r][c4 * 4] = vv;
    }
  }
  const float* Wm[4] = {W0, W1, W2, W3};
  const float* Bm[4] = {B0, B1, B2, B3};
  float* Om[4] = {O0, O1, O2, O3};
  const int rg = t / CG, cg = t % CG;
  const int r0 = rg * 4, c0 = cg * 4;
  #pragma unroll
  for (int m = 0; m < 4; ++m) {
    const float4 bias = *(const float4*)&Bm[m][c0];
    float4 acc0 = bias, acc1 = bias, acc2 = bias, acc3 = bias;
    #pragma unroll
    for (int half = 0; half < 2; ++half) {
      __syncthreads();
      {  // stage W rows [half*64, half*64+64)
        const int nv = 64 * (DOUT / 4);
        const float4* Wg = (const float4*)(Wm[m] + (size_t)half * 64 * DOUT);
        float4* Wl4 = (float4*)&Wl[0][0];
        for (int i = t; i < nv; i += 256) Wl4[i] = Wg[i];
      }
      __syncthreads();
      const int hb = half * 64;
      #pragma unroll 4
      for (int k4 = 0; k4 < 64; k4 += 4) {
        const float4 w0v = *(const float4*)&Wl[k4 + 0][c0];
        const float4 w1v = *(const float4*)&Wl[k4 + 1][c0];
        const float4 w2v = *(const float4*)&Wl[k4 + 2][c0];
        const float4 w3v = *(const float4*)&Wl[k4 + 3][c0];
        const float4 xa = *(const float4*)&Xs[r0 + 0][hb + k4];
        const float4 xb = *(const float4*)&Xs[r0 + 1][hb + k4];
        const float4 xc = *(const float4*)&Xs[r0 + 2][hb + k4];
        const float4 xd = *(const float4*)&Xs[r0 + 3][hb + k4];
        acc0 = f4fma(acc0, xa.x, w0v); acc0 = f4fma(acc0, xa.y, w1v);
        acc0 = f4fma(acc0, xa.z, w2v); acc0 = f4fma(acc0, xa.w, w3v);
        acc1 = f4fma(acc1, xb.x, w0v); acc1 = f4fma(acc1, xb.y, w1v);
        acc1 = f4fma(acc1, xb.z, w2v); acc1 = f4fma(acc1, xb.w, w3v);
        acc2 = f4fma(acc2, xc.x, w0v); acc2 = f4fma(acc2, xc.y, w1v);
        acc2 = f4fma(acc2, xc.z, w2v); acc2 = f4fma(acc2, xc.w, w3v);
        acc3 = f4fma(acc3, xd.x, w0v); acc3 = f4fma(acc3, xd.y, w1v);
        acc3 = f4fma(acc3, xd.z, w2v); acc3 = f4fma(acc3, xd.w, w3v);
      }
    }
    if (row0 + r0 + 0 < nrows) *(float4*)&Om[m][(size_t)(row0 + r0 + 0) * DOUT + c0] = acc0;
    if (row0 + r0 + 1 < nrows) *(float4*)&Om[m][(size_t)(row0 + r0 + 1) * DOUT + c0] = acc1;
    if (row0 + r0 + 2 < nrows) *(float4*)&Om[m][(size_t)(row0 + r0 + 2) * DOUT + c0] = acc2;
    if (row0 + r0 + 3 < nrows) *(float4*)&Om[m][(size_t)(row0 + r0 + 3) * DOUT + c0] = acc3;
  }
}

// ---------------------------------------------------------------- attention
// Layer 1: heads=8, C=16, concat. 16 lanes per dst node; lane owns 8 channels
// (head = sub/2), online softmax per head tracked redundantly in the lane pair.
__global__ __launch_bounds__(256)
void attn_l1(const float* __restrict__ q, const float* __restrict__ k,
             const float* __restrict__ v, const float* __restrict__ skip,
             const int* __restrict__ rowp, const int* __restrict__ cidx,
             float* __restrict__ h) {
  const int node = blockIdx.x * 16 + (threadIdx.x >> 4);
  const int sub = threadIdx.x & 15;
  if (node >= NN) return;
  const int cb = sub * 8;
  float4 q0 = *(const float4*)&q[(size_t)node * 128 + cb];
  float4 q1 = *(const float4*)&q[(size_t)node * 128 + cb + 4];
  const float sc = 0.25f;  // 1/sqrt(16)
  q0.x *= sc; q0.y *= sc; q0.z *= sc; q0.w *= sc;
  q1.x *= sc; q1.y *= sc; q1.z *= sc; q1.w *= sc;
  float m = -INFINITY, s = 0.f;
  float4 a0 = make_float4(0.f, 0.f, 0.f, 0.f);
  float4 a1 = make_float4(0.f, 0.f, 0.f, 0.f);
  const int e0 = rowp[node], e1 = rowp[node + 1];
  for (int e = e0; e < e1; ++e) {
    const int src = cidx[e];
    const float4 k0 = *(const float4*)&k[(size_t)src * 128 + cb];
    const float4 k1v = *(const float4*)&k[(size_t)src * 128 + cb + 4];
    float pd = q0.x * k0.x + q0.y * k0.y + q0.z * k0.z + q0.w * k0.w +
               q1.x * k1v.x + q1.y * k1v.y + q1.z * k1v.z + q1.w * k1v.w;
    const float alpha = pd + __shfl_xor(pd, 1);   // full 16-dim head dot
    const float nm = fmaxf(m, alpha);
    const float corr = __expf(m - nm);
    const float p = __expf(alpha - nm);
    s = s * corr + p;
    const float4 v0 = *(const float4*)&v[(size_t)src * 128 + cb];
    const float4 v1v = *(const float4*)&v[(size_t)src * 128 + cb + 4];
    a0.x = fmaf(p, v0.x, a0.x * corr);  a0.y = fmaf(p, v0.y, a0.y * corr);
    a0.z = fmaf(p, v0.z, a0.z * corr);  a0.w = fmaf(p, v0.w, a0.w * corr);
    a1.x = fmaf(p, v1v.x, a1.x * corr); a1.y = fmaf(p, v1v.y, a1.y * corr);
    a1.z = fmaf(p, v1v.z, a1.z * corr); a1.w = fmaf(p, v1v.w, a1.w * corr);
    m = nm;
  }
  const float inv = (e1 > e0) ? 1.f / s : 0.f;
  const float4 sk0 = *(const float4*)&skip[(size_t)node * 128 + cb];
  const float4 sk1 = *(const float4*)&skip[(size_t)node * 128 + cb + 4];
  float4 o0, o1;
  o0.x = fmaxf(fmaf(a0.x, inv, sk0.x), 0.f);
  o0.y = fmaxf(fmaf(a0.y, inv, sk0.y), 0.f);
  o0.z = fmaxf(fmaf(a0.z, inv, sk0.z), 0.f);
  o0.w = fmaxf(fmaf(a0.w, inv, sk0.w), 0.f);
  o1.x = fmaxf(fmaf(a1.x, inv, sk1.x), 0.f);
  o1.y = fmaxf(fmaf(a1.y, inv, sk1.y), 0.f);
  o1.z = fmaxf(fmaf(a1.z, inv, sk1.z), 0.f);
  o1.w = fmaxf(fmaf(a1.w, inv, sk1.w), 0.f);
  *(float4*)&h[(size_t)node * 128 + cb] = o0;
  *(float4*)&h[(size_t)node * 128 + cb + 4] = o1;
}

// Layer 2: heads=1, C=64, mean(=identity) + skip. 16 lanes per dst node,
// lane owns 4 channels; 16-lane shuffle reduction for the 64-dim dot.
__global__ __launch_bounds__(256)
void attn_l2(const float* __restrict__ q, const float* __restrict__ k,
             const float* __restrict__ v, const float* __restrict__ skip,
             const int* __restrict__ rowp, const int* __restrict__ cidx,
             float* __restrict__ out) {
  const int node = blockIdx.x * 16 + (threadIdx.x >> 4);
  const int sub = threadIdx.x & 15;
  if (node >= NN) return;
  const int cb = sub * 4;
  float4 qv = *(const float4*)&q[(size_t)node * 64 + cb];
  const float sc = 0.125f;  // 1/sqrt(64)
  qv.x *= sc; qv.y *= sc; qv.z *= sc; qv.w *= sc;
  float m = -INFINITY, s = 0.f;
  float4 acc = make_float4(0.f, 0.f, 0.f, 0.f);
  const int e0 = rowp[node], e1 = rowp[node + 1];
  for (int e = e0; e < e1; ++e) {
    const int src = cidx[e];
    const float4 kv = *(const float4*)&k[(size_t)src * 64 + cb];
    float pd = qv.x * kv.x + qv.y * kv.y + qv.z * kv.z + qv.w * kv.w;
    pd += __shfl_xor(pd, 1);
    pd += __shfl_xor(pd, 2);
    pd += __shfl_xor(pd, 4);
    pd += __shfl_xor(pd, 8);
    const float alpha = pd;
    const float nm = fmaxf(m, alpha);
    const float corr = __expf(m - nm);
    const float p = __expf(alpha - nm);
    s = s * corr + p;
    const float4 vv = *(const float4*)&v[(size_t)src * 64 + cb];
    acc.x = fmaf(p, vv.x, acc.x * corr);
    acc.y = fmaf(p, vv.y, acc.y * corr);
    acc.z = fmaf(p, vv.z, acc.z * corr);
    acc.w = fmaf(p, vv.w, acc.w * corr);
    m = nm;
  }
  const float inv = (e1 > e0) ? 1.f / s : 0.f;
  const float4 sk = *(const float4*)&skip[(size_t)node * 64 + cb];
  float4 o;
  o.x = fmaf(acc.x, inv, sk.x);
  o.y = fmaf(acc.y, inv, sk.y);
  o.z = fmaf(acc.z, inv, sk.z);
  o.w = fmaf(acc.w, inv, sk.w);
  *(float4*)&out[(size_t)node * 64 + cb] = o;
}

// ---------------------------------------------------------------- launch
extern "C" void kernel_launch(void* const* d_in, const int* in_sizes, int n_in,
                              void* d_out, int out_size, void* d_ws, size_t ws_size,
                              hipStream_t stream) {
  const float* x = (const float*)d_in[0];
  const int* ei = (const int*)d_in[1];
  const int* esrc = ei;        // edge_index[0]
  const int* edst = ei + NE;   // edge_index[1]
  const float* Wq1 = (const float*)d_in[2];  const float* bq1 = (const float*)d_in[3];
  const float* Wk1 = (const float*)d_in[4];  const float* bk1 = (const float*)d_in[5];
  const float* Wv1 = (const float*)d_in[6];  const float* bv1 = (const float*)d_in[7];
  const float* Ws1 = (const float*)d_in[8];  const float* bs1 = (const float*)d_in[9];
  const float* Wq2 = (const float*)d_in[10]; const float* bq2 = (const float*)d_in[11];
  const float* Wk2 = (const float*)d_in[12]; const float* bk2 = (const float*)d_in[13];
  const float* Wv2 = (const float*)d_in[14]; const float* bv2 = (const float*)d_in[15];
  const float* Ws2 = (const float*)d_in[16]; const float* bs2 = (const float*)d_in[17];
  float* out = (float*)d_out;

  float* f = (float*)d_ws;
  const size_t NC = (size_t)NN * 128;
  float* q1 = f;
  float* k1 = f + NC;
  float* v1 = f + 2 * NC;
  float* sk1 = f + 3 * NC;
  float* h = f + 4 * NC;
  const size_t NC2 = (size_t)NN * 64;
  // layer-2 projections reuse layer-1 space (consumed before gemm4<64> runs)
  float* q2 = f;
  float* k2 = f + NC2;
  float* v2 = f + 2 * NC2;
  float* sk2 = f + 3 * NC2;
  int* ip = (int*)(f + 5 * NC);
  int* deg = ip;                 // NN
  int* rowp = ip + NN;           // NN+1
  int* bsum = ip + 2 * NN + 1;   // 128
  int* cursor = bsum + 128;      // NN
  int* cidx = cursor + NN;       // NE

  // ---- CSR build (by dst) ----
  hipMemsetAsync(deg, 0, NN * sizeof(int), stream);
  hist_k<<<2048, 256, 0, stream>>>(edst, deg);
  scan1_k<<<(NN + 1023) / 1024, 256, 0, stream>>>(deg, rowp + 1, bsum);
  scan2_k<<<1, 128, 0, stream>>>(bsum, (NN + 1023) / 1024);
  scan3_k<<<(NN + 255) / 256, 256, 0, stream>>>(rowp, bsum);
  hipMemcpyAsync(cursor, rowp, NN * sizeof(int), hipMemcpyDeviceToDevice, stream);
  fill_k<<<2048, 256, 0, stream>>>(esrc, edst, cursor, cidx);

  // ---- layer 1 ----
  gemm4_k<128><<<NN / 32, 256, 0, stream>>>(x, NN,
      Wq1, bq1, q1, Wk1, bk1, k1, Wv1, bv1, v1, Ws1, bs1, sk1);
  attn_l1<<<(NN + 15) / 16, 256, 0, stream>>>(q1, k1, v1, sk1, rowp, cidx, h);

  // ---- layer 2 ----
  gemm4_k<64><<<(NN + 63) / 64, 256, 0, stream>>>(h, NN,
      Wq2, bq2, q2, Wk2, bk2, k2, Wv2, bv2, v2, Ws2, bs2, sk2);
  attn_l2<<<(NN + 15) / 16, 256, 0, stream>>>(q2, k2, v2, sk2, rowp, cidx, out);
}

// Round 2
// 748.074 us; speedup vs baseline: 1.2334x; 1.2334x over previous
//
#include <hip/hip_runtime.h>
#include <math.h>

#define NN 100000
#define NE 1600000

typedef __attribute__((ext_vector_type(8))) short bf16x8;
typedef __attribute__((ext_vector_type(4))) float f32x4;

// ---------------------------------------------------------------- bf16 utils
__device__ __forceinline__ unsigned short f2bf(float x) {
  unsigned int u = __float_as_uint(x);
  u += 0x7fffu + ((u >> 16) & 1u);   // RNE
  return (unsigned short)(u >> 16);
}
__device__ __forceinline__ float bf2f(unsigned short b) {
  return __uint_as_float(((unsigned int)b) << 16);
}
__device__ __forceinline__ void unpack8(uint4 u, float* f) {
  f[0] = __uint_as_float(u.x << 16); f[1] = __uint_as_float(u.x & 0xffff0000u);
  f[2] = __uint_as_float(u.y << 16); f[3] = __uint_as_float(u.y & 0xffff0000u);
  f[4] = __uint_as_float(u.z << 16); f[5] = __uint_as_float(u.z & 0xffff0000u);
  f[6] = __uint_as_float(u.w << 16); f[7] = __uint_as_float(u.w & 0xffff0000u);
}

// ---------------------------------------------------------------- CSR build
__global__ void hist_k(const int* __restrict__ dst, int* __restrict__ deg) {
  for (int e = blockIdx.x * blockDim.x + threadIdx.x; e < NE;
       e += gridDim.x * blockDim.x)
    atomicAdd(&deg[dst[e]], 1);
}

__global__ __launch_bounds__(256)
void scan1_k(const int* __restrict__ deg, int* __restrict__ rowp1,
             int* __restrict__ bsum) {
  __shared__ int wsum[4];
  const int t = threadIdx.x;
  const int i0 = blockIdx.x * 1024 + t * 4;
  int v0 = (i0 + 0 < NN) ? deg[i0 + 0] : 0;
  int v1 = (i0 + 1 < NN) ? deg[i0 + 1] : 0;
  int v2 = (i0 + 2 < NN) ? deg[i0 + 2] : 0;
  int v3 = (i0 + 3 < NN) ? deg[i0 + 3] : 0;
  const int s1 = v0 + v1, s2 = s1 + v2, s3 = s2 + v3;
  const int tsum = s3;
  const int lane = t & 63;
  int incl = tsum;
  #pragma unroll
  for (int off = 1; off < 64; off <<= 1) {
    int n = __shfl_up(incl, off);
    if (lane >= off) incl += n;
  }
  const int wid = t >> 6;
  if (lane == 63) wsum[wid] = incl;
  __syncthreads();
  int woff = 0;
  for (int w = 0; w < wid; ++w) woff += wsum[w];
  const int texcl = incl - tsum + woff;
  if (i0 + 0 < NN) rowp1[i0 + 0] = texcl + v0;
  if (i0 + 1 < NN) rowp1[i0 + 1] = texcl + s1;
  if (i0 + 2 < NN) rowp1[i0 + 2] = texcl + s2;
  if (i0 + 3 < NN) rowp1[i0 + 3] = texcl + s3;
  if (t == 255) bsum[blockIdx.x] = texcl + tsum;
}

__global__ void scan2_k(int* __restrict__ bsum, int nb) {
  __shared__ int sh[128];
  const int t = threadIdx.x;
  const int v = (t < nb) ? bsum[t] : 0;
  sh[t] = v;
  __syncthreads();
  #pragma unroll
  for (int off = 1; off < 128; off <<= 1) {
    int nv = (t >= off) ? sh[t - off] : 0;
    __syncthreads();
    sh[t] += nv;
    __syncthreads();
  }
  if (t < nb) bsum[t] = sh[t] - v;
}

__global__ void scan3_k(int* __restrict__ rowp, const int* __restrict__ bsum) {
  const int i = blockIdx.x * blockDim.x + threadIdx.x;
  if (i == 0) rowp[0] = 0;
  if (i < NN) rowp[i + 1] += bsum[i >> 10];
}

__global__ void fill_k(const int* __restrict__ src, const int* __restrict__ dst,
                       int* __restrict__ cursor, int* __restrict__ cidx) {
  for (int e = blockIdx.x * blockDim.x + threadIdx.x; e < NE;
       e += gridDim.x * blockDim.x) {
    const int d = dst[e];
    const int pos = atomicAdd(&cursor[d], 1);
    cidx[pos] = src[e];
  }
}

// ---------------------------------------------------------------- W convert
// W[din][dout] f32 -> Wt hi/lo planes [dout][din] bf16 (transposed, split)
struct WConv { const float* src; unsigned short* hi; unsigned short* lo; int dout; };
struct WConv8 { WConv m[8]; };

__global__ void wconv_k(WConv8 a) {
  const WConv w = a.m[blockIdx.x];
  const int n = 128 * w.dout;
  for (int i = threadIdx.x; i < n; i += blockDim.x) {
    const int c = i >> 7, kk = i & 127;  // out idx = c*128 + kk
    const float x = w.src[(size_t)kk * w.dout + c];
    const unsigned short h = f2bf(x);
    w.hi[i] = h;
    w.lo[i] = f2bf(x - bf2f(h));
  }
}

// ---------------------------------------------------------------- GEMM x4 (MFMA)
// O_m = X @ W_m + b_m, K=128. Split-bf16: X=Xh+Xl, W=Wh+Wl,
// acc = Xh*Wh + Xl*Wh + Xh*Wl (f32 accumulate). BM=128 rows/block, 4 waves.
struct GMat { const unsigned short* wh; const unsigned short* wl;
              const float* bias; float* outf; unsigned short* outb; };
struct GArgs { GMat m[4]; };

template <int DOUT, bool PRESPLIT>
__global__ __launch_bounds__(256, 1)
void gemm4_mfma(const float* __restrict__ X,
                const unsigned short* __restrict__ Xh,
                const unsigned short* __restrict__ Xl,
                int nrows, GArgs ga) {
  constexpr int BM = 128, KP = 136, NF = DOUT / 16;
  __shared__ __align__(16) unsigned short Ah[BM * KP];
  __shared__ __align__(16) unsigned short Al[BM * KP];
  __shared__ __align__(16) unsigned short Bh[DOUT * KP];
  __shared__ __align__(16) unsigned short Bl[DOUT * KP];
  const int t = threadIdx.x;
  const int row0 = blockIdx.x * BM;

  // ---- stage A (hi/lo) ----
  if constexpr (!PRESPLIT) {
    for (int i = t; i < BM * 32; i += 256) {
      const int r = i >> 5, c = (i & 31) << 2;
      float4 xv = make_float4(0.f, 0.f, 0.f, 0.f);
      if (row0 + r < nrows) xv = *(const float4*)&X[(size_t)(row0 + r) * 128 + c];
      const unsigned short h0 = f2bf(xv.x), h1 = f2bf(xv.y),
                           h2 = f2bf(xv.z), h3 = f2bf(xv.w);
      uint2 hp, lp;
      hp.x = (unsigned)h0 | ((unsigned)h1 << 16);
      hp.y = (unsigned)h2 | ((unsigned)h3 << 16);
      lp.x = (unsigned)f2bf(xv.x - bf2f(h0)) | ((unsigned)f2bf(xv.y - bf2f(h1)) << 16);
      lp.y = (unsigned)f2bf(xv.z - bf2f(h2)) | ((unsigned)f2bf(xv.w - bf2f(h3)) << 16);
      *(uint2*)&Ah[r * KP + c] = hp;
      *(uint2*)&Al[r * KP + c] = lp;
    }
  } else {
    for (int i = t; i < BM * 16; i += 256) {
      const int r = i >> 4, c = (i & 15) << 3;
      uint4 hv = make_uint4(0, 0, 0, 0), lv = hv;
      if (row0 + r < nrows) {
        hv = *(const uint4*)&Xh[(size_t)(row0 + r) * 128 + c];
        lv = *(const uint4*)&Xl[(size_t)(row0 + r) * 128 + c];
      }
      *(uint4*)&Ah[r * KP + c] = hv;
      *(uint4*)&Al[r * KP + c] = lv;
    }
  }
  // ---- stage B for m=0 ----
  for (int i = t; i < DOUT * 16; i += 256) {
    const int r = i >> 4, c = (i & 15) << 3;
    *(uint4*)&Bh[r * KP + c] = *(const uint4*)&ga.m[0].wh[(size_t)r * 128 + c];
    *(uint4*)&Bl[r * KP + c] = *(const uint4*)&ga.m[0].wl[(size_t)r * 128 + c];
  }
  __syncthreads();

  const int w = t >> 6, l = t & 63;
  const int lr = l & 15, lg = l >> 4;
  // A fragments for this wave's 32 rows, register-resident for all 4 matrices
  bf16x8 ah[2][4], al[2][4];
  #pragma unroll
  for (int mf = 0; mf < 2; ++mf)
    #pragma unroll
    for (int ks = 0; ks < 4; ++ks) {
      const int off = (w * 32 + mf * 16 + lr) * KP + ks * 32 + lg * 8;
      ah[mf][ks] = *(const bf16x8*)&Ah[off];
      al[mf][ks] = *(const bf16x8*)&Al[off];
    }

  for (int m = 0; m < 4; ++m) {
    const GMat gm = ga.m[m];
    #pragma unroll
    for (int nf = 0; nf < NF; ++nf) {
      bf16x8 bh[4], bl[4];
      #pragma unroll
      for (int ks = 0; ks < 4; ++ks) {
        const int off = (nf * 16 + lr) * KP + ks * 32 + lg * 8;
        bh[ks] = *(const bf16x8*)&Bh[off];
        bl[ks] = *(const bf16x8*)&Bl[off];
      }
      f32x4 acc0 = {0.f, 0.f, 0.f, 0.f}, acc1 = {0.f, 0.f, 0.f, 0.f};
      #pragma unroll
      for (int ks = 0; ks < 4; ++ks) {
        acc0 = __builtin_amdgcn_mfma_f32_16x16x32_bf16(ah[0][ks], bh[ks], acc0, 0, 0, 0);
        acc1 = __builtin_amdgcn_mfma_f32_16x16x32_bf16(ah[1][ks], bh[ks], acc1, 0, 0, 0);
        acc0 = __builtin_amdgcn_mfma_f32_16x16x32_bf16(al[0][ks], bh[ks], acc0, 0, 0, 0);
        acc1 = __builtin_amdgcn_mfma_f32_16x16x32_bf16(al[1][ks], bh[ks], acc1, 0, 0, 0);
        acc0 = __builtin_amdgcn_mfma_f32_16x16x32_bf16(ah[0][ks], bl[ks], acc0, 0, 0, 0);
        acc1 = __builtin_amdgcn_mfma_f32_16x16x32_bf16(ah[1][ks], bl[ks], acc1, 0, 0, 0);
      }
      const int col = nf * 16 + lr;
      const float bb = gm.bias[col];
      #pragma unroll
      for (int j = 0; j < 4; ++j) {
        const int r0 = row0 + w * 32 + lg * 4 + j;   // C/D: row=(l>>4)*4+reg
        const int r1 = r0 + 16;
        if (gm.outb) {
          if (r0 < nrows) gm.outb[(size_t)r0 * DOUT + col] = f2bf(acc0[j] + bb);
          if (r1 < nrows) gm.outb[(size_t)r1 * DOUT + col] = f2bf(acc1[j] + bb);
        } else {
          if (r0 < nrows) gm.outf[(size_t)r0 * DOUT + col] = acc0[j] + bb;
          if (r1 < nrows) gm.outf[(size_t)r1 * DOUT + col] = acc1[j] + bb;
        }
      }
    }
    __syncthreads();
    if (m < 3) {
      const GMat gn = ga.m[m + 1];
      for (int i = t; i < DOUT * 16; i += 256) {
        const int r = i >> 4, c = (i & 15) << 3;
        *(uint4*)&Bh[r * KP + c] = *(const uint4*)&gn.wh[(size_t)r * 128 + c];
        *(uint4*)&Bl[r * KP + c] = *(const uint4*)&gn.wl[(size_t)r * 128 + c];
      }
      __syncthreads();
    }
  }
}

// ---------------------------------------------------------------- attention
// Layer 1: heads=8, C=16, concat. 8 lanes/node, one head per lane.
// No max-shift: |logit| = |q.k|/4 is O(10), exp() safe in f32.
__global__ __launch_bounds__(256)
void attn1_k(const unsigned short* __restrict__ q, const unsigned short* __restrict__ k,
             const unsigned short* __restrict__ v, const float* __restrict__ skip,
             const int* __restrict__ rowp, const int* __restrict__ cidx,
             unsigned short* __restrict__ hhi, unsigned short* __restrict__ hlo) {
  const int node = blockIdx.x * 32 + (threadIdx.x >> 3);
  if (node >= NN) return;
  const int cb = (threadIdx.x & 7) * 16;
  float qv[16];
  {
    uint4 q0 = *(const uint4*)&q[(size_t)node * 128 + cb];
    uint4 q1 = *(const uint4*)&q[(size_t)node * 128 + cb + 8];
    unpack8(q0, qv); unpack8(q1, qv + 8);
    #pragma unroll
    for (int c = 0; c < 16; ++c) qv[c] *= 0.25f;  // 1/sqrt(16)
  }
  float s = 0.f, acc[16];
  #pragma unroll
  for (int c = 0; c < 16; ++c) acc[c] = 0.f;
  const int e0 = rowp[node], e1 = rowp[node + 1];
  for (int e = e0; e < e1; ++e) {
    const int src = cidx[e];
    uint4 k0 = *(const uint4*)&k[(size_t)src * 128 + cb];
    uint4 k1 = *(const uint4*)&k[(size_t)src * 128 + cb + 8];
    float kv[16]; unpack8(k0, kv); unpack8(k1, kv + 8);
    float d = 0.f;
    #pragma unroll
    for (int c = 0; c < 16; ++c) d = fmaf(qv[c], kv[c], d);
    const float p = __expf(d);
    s += p;
    uint4 v0 = *(const uint4*)&v[(size_t)src * 128 + cb];
    uint4 v1 = *(const uint4*)&v[(size_t)src * 128 + cb + 8];
    float vv[16]; unpack8(v0, vv); unpack8(v1, vv + 8);
    #pragma unroll
    for (int c = 0; c < 16; ++c) acc[c] = fmaf(p, vv[c], acc[c]);
  }
  const float inv = (e1 > e0) ? 1.f / s : 0.f;
  float sk[16];
  {
    const float* sp = &skip[(size_t)node * 128 + cb];
    *(float4*)&sk[0]  = *(const float4*)&sp[0];
    *(float4*)&sk[4]  = *(const float4*)&sp[4];
    *(float4*)&sk[8]  = *(const float4*)&sp[8];
    *(float4*)&sk[12] = *(const float4*)&sp[12];
  }
  unsigned int hw[8], lw[8];
  #pragma unroll
  for (int c2 = 0; c2 < 8; ++c2) {
    const float oa = fmaxf(fmaf(acc[2 * c2], inv, sk[2 * c2]), 0.f);
    const float ob = fmaxf(fmaf(acc[2 * c2 + 1], inv, sk[2 * c2 + 1]), 0.f);
    const unsigned short ha = f2bf(oa), hb = f2bf(ob);
    hw[c2] = (unsigned)ha | ((unsigned)hb << 16);
    lw[c2] = (unsigned)f2bf(oa - bf2f(ha)) | ((unsigned)f2bf(ob - bf2f(hb)) << 16);
  }
  uint4* HH = (uint4*)&hhi[(size_t)node * 128 + cb];
  uint4* LL = (uint4*)&hlo[(size_t)node * 128 + cb];
  HH[0] = make_uint4(hw[0], hw[1], hw[2], hw[3]);
  HH[1] = make_uint4(hw[4], hw[5], hw[6], hw[7]);
  LL[0] = make_uint4(lw[0], lw[1], lw[2], lw[3]);
  LL[1] = make_uint4(lw[4], lw[5], lw[6], lw[7]);
}

// Layer 2: heads=1, C=64. 8 lanes/node, 8 ch/lane, 3x shfl_xor dot-reduce.
__global__ __launch_bounds__(256)
void attn2_k(const unsigned short* __restrict__ q, const unsigned short* __restrict__ k,
             const unsigned short* __restrict__ v, const float* __restrict__ skip,
             const int* __restrict__ rowp, const int* __restrict__ cidx,
             float* __restrict__ out) {
  const int node = blockIdx.x * 32 + (threadIdx.x >> 3);
  if (node >= NN) return;
  const int cb = (threadIdx.x & 7) * 8;
  float qv[8];
  {
    uint4 q0 = *(const uint4*)&q[(size_t)node * 64 + cb];
    unpack8(q0, qv);
    #pragma unroll
    for (int c = 0; c < 8; ++c) qv[c] *= 0.125f;  // 1/sqrt(64)
  }
  float s = 0.f, acc[8];
  #pragma unroll
  for (int c = 0; c < 8; ++c) acc[c] = 0.f;
  const int e0 = rowp[node], e1 = rowp[node + 1];
  for (int e = e0; e < e1; ++e) {
    const int src = cidx[e];
    uint4 kk = *(const uint4*)&k[(size_t)src * 64 + cb];
    float kv[8]; unpack8(kk, kv);
    float d = 0.f;
    #pragma unroll
    for (int c = 0; c < 8; ++c) d = fmaf(qv[c], kv[c], d);
    d += __shfl_xor(d, 1);
    d += __shfl_xor(d, 2);
    d += __shfl_xor(d, 4);
    const float p = __expf(d);
    s += p;
    uint4 vv4 = *(const uint4*)&v[(size_t)src * 64 + cb];
    float vv[8]; unpack8(vv4, vv);
    #pragma unroll
    for (int c = 0; c < 8; ++c) acc[c] = fmaf(p, vv[c], acc[c]);
  }
  const float inv = (e1 > e0) ? 1.f / s : 0.f;
  const float* sp = &skip[(size_t)node * 64 + cb];
  float4 o0, o1;
  o0.x = fmaf(acc[0], inv, sp[0]); o0.y = fmaf(acc[1], inv, sp[1]);
  o0.z = fmaf(acc[2], inv, sp[2]); o0.w = fmaf(acc[3], inv, sp[3]);
  o1.x = fmaf(acc[4], inv, sp[4]); o1.y = fmaf(acc[5], inv, sp[5]);
  o1.z = fmaf(acc[6], inv, sp[6]); o1.w = fmaf(acc[7], inv, sp[7]);
  *(float4*)&out[(size_t)node * 64 + cb] = o0;
  *(float4*)&out[(size_t)node * 64 + cb + 4] = o1;
}

// ---------------------------------------------------------------- launch
extern "C" void kernel_launch(void* const* d_in, const int* in_sizes, int n_in,
                              void* d_out, int out_size, void* d_ws, size_t ws_size,
                              hipStream_t stream) {
  const float* x = (const float*)d_in[0];
  const int* ei = (const int*)d_in[1];
  const int* esrc = ei;
  const int* edst = ei + NE;
  const float* Wf[8] = {(const float*)d_in[2],  (const float*)d_in[4],
                        (const float*)d_in[6],  (const float*)d_in[8],
                        (const float*)d_in[10], (const float*)d_in[12],
                        (const float*)d_in[14], (const float*)d_in[16]};
  const float* Bf[8] = {(const float*)d_in[3],  (const float*)d_in[5],
                        (const float*)d_in[7],  (const float*)d_in[9],
                        (const float*)d_in[11], (const float*)d_in[13],
                        (const float*)d_in[15], (const float*)d_in[17]};
  float* out = (float*)d_out;

  char* p = (char*)d_ws;
  auto alloc = [&](size_t b) { char* r = p; p += (b + 255) & ~(size_t)255; return r; };
  unsigned short* q1 = (unsigned short*)alloc((size_t)NN * 128 * 2);
  unsigned short* k1 = (unsigned short*)alloc((size_t)NN * 128 * 2);
  unsigned short* v1 = (unsigned short*)alloc((size_t)NN * 128 * 2);
  float*          sk1 = (float*)alloc((size_t)NN * 128 * 4);
  unsigned short* hh = (unsigned short*)alloc((size_t)NN * 128 * 2);
  unsigned short* hl = (unsigned short*)alloc((size_t)NN * 128 * 2);
  unsigned short* q2 = (unsigned short*)alloc((size_t)NN * 64 * 2);
  unsigned short* k2 = (unsigned short*)alloc((size_t)NN * 64 * 2);
  unsigned short* v2 = (unsigned short*)alloc((size_t)NN * 64 * 2);
  float*          sk2 = (float*)alloc((size_t)NN * 64 * 4);
  unsigned short* wh[8];
  unsigned short* wl[8];
  for (int i = 0; i < 8; ++i) {
    const int dout = (i < 4) ? 128 : 64;
    wh[i] = (unsigned short*)alloc((size_t)128 * dout * 2);
    wl[i] = (unsigned short*)alloc((size_t)128 * dout * 2);
  }
  int* deg = (int*)alloc((size_t)NN * 4);
  int* rowp = (int*)alloc((size_t)(NN + 1) * 4);
  int* bsum = (int*)alloc(128 * 4);
  int* cursor = (int*)alloc((size_t)NN * 4);
  int* cidx = (int*)alloc((size_t)NE * 4);

  // ---- W convert (transpose + hi/lo split) ----
  WConv8 wc;
  for (int i = 0; i < 8; ++i) wc.m[i] = {Wf[i], wh[i], wl[i], (i < 4) ? 128 : 64};
  wconv_k<<<8, 256, 0, stream>>>(wc);

  // ---- CSR build (by dst) ----
  hipMemsetAsync(deg, 0, NN * sizeof(int), stream);
  hist_k<<<2048, 256, 0, stream>>>(edst, deg);
  scan1_k<<<(NN + 1023) / 1024, 256, 0, stream>>>(deg, rowp + 1, bsum);
  scan2_k<<<1, 128, 0, stream>>>(bsum, (NN + 1023) / 1024);
  scan3_k<<<(NN + 255) / 256, 256, 0, stream>>>(rowp, bsum);
  hipMemcpyAsync(cursor, rowp, NN * sizeof(int), hipMemcpyDeviceToDevice, stream);
  fill_k<<<2048, 256, 0, stream>>>(esrc, edst, cursor, cidx);

  // ---- layer 1 ----
  GArgs g1;
  g1.m[0] = {wh[0], wl[0], Bf[0], nullptr, q1};
  g1.m[1] = {wh[1], wl[1], Bf[1], nullptr, k1};
  g1.m[2] = {wh[2], wl[2], Bf[2], nullptr, v1};
  g1.m[3] = {wh[3], wl[3], Bf[3], sk1, nullptr};
  gemm4_mfma<128, false><<<(NN + 127) / 128, 256, 0, stream>>>(x, nullptr, nullptr, NN, g1);
  attn1_k<<<(NN + 31) / 32, 256, 0, stream>>>(q1, k1, v1, sk1, rowp, cidx, hh, hl);

  // ---- layer 2 ----
  GArgs g2;
  g2.m[0] = {wh[4], wl[4], Bf[4], nullptr, q2};
  g2.m[1] = {wh[5], wl[5], Bf[5], nullptr, k2};
  g2.m[2] = {wh[6], wl[6], Bf[6], nullptr, v2};
  g2.m[3] = {wh[7], wl[7], Bf[7], sk2, nullptr};
  gemm4_mfma<64, true><<<(NN + 127) / 128, 256, 0, stream>>>(nullptr, hh, hl, NN, g2);
  attn2_k<<<(NN + 31) / 32, 256, 0, stream>>>(q2, k2, v2, sk2, rowp, cidx, out);
}

// Round 3
// 652.444 us; speedup vs baseline: 1.4142x; 1.1466x over previous
//
#include <hip/hip_runtime.h>
#include <math.h>

#define NN 100000
#define NE 1600000

typedef __attribute__((ext_vector_type(8))) short bf16x8;
typedef __attribute__((ext_vector_type(4))) float f32x4;

// ---------------------------------------------------------------- bf16 utils
__device__ __forceinline__ unsigned short f2bf(float x) {
  unsigned int u = __float_as_uint(x);
  u += 0x7fffu + ((u >> 16) & 1u);   // RNE
  return (unsigned short)(u >> 16);
}
__device__ __forceinline__ float bf2f(unsigned short b) {
  return __uint_as_float(((unsigned int)b) << 16);
}
__device__ __forceinline__ void unpack8(uint4 u, float* f) {
  f[0] = __uint_as_float(u.x << 16); f[1] = __uint_as_float(u.x & 0xffff0000u);
  f[2] = __uint_as_float(u.y << 16); f[3] = __uint_as_float(u.y & 0xffff0000u);
  f[4] = __uint_as_float(u.z << 16); f[5] = __uint_as_float(u.z & 0xffff0000u);
  f[6] = __uint_as_float(u.w << 16); f[7] = __uint_as_float(u.w & 0xffff0000u);
}
__device__ __forceinline__ void split8(const float* f, bf16x8& h8, bf16x8& l8) {
  union { bf16x8 v; unsigned short s[8]; } H, L;
  #pragma unroll
  for (int j = 0; j < 8; ++j) {
    const unsigned short hh = f2bf(f[j]);
    H.s[j] = hh;
    L.s[j] = f2bf(f[j] - bf2f(hh));
  }
  h8 = H.v; l8 = L.v;
}

// ---------------------------------------------------------------- CSR build
__global__ void hist_k(const int* __restrict__ dst, int* __restrict__ deg) {
  for (int e = blockIdx.x * blockDim.x + threadIdx.x; e < NE;
       e += gridDim.x * blockDim.x)
    atomicAdd(&deg[dst[e]], 1);
}

__global__ __launch_bounds__(256)
void scan1_k(const int* __restrict__ deg, int* __restrict__ rowp1,
             int* __restrict__ bsum) {
  __shared__ int wsum[4];
  const int t = threadIdx.x;
  const int i0 = blockIdx.x * 1024 + t * 4;
  int v0 = (i0 + 0 < NN) ? deg[i0 + 0] : 0;
  int v1 = (i0 + 1 < NN) ? deg[i0 + 1] : 0;
  int v2 = (i0 + 2 < NN) ? deg[i0 + 2] : 0;
  int v3 = (i0 + 3 < NN) ? deg[i0 + 3] : 0;
  const int s1 = v0 + v1, s2 = s1 + v2, s3 = s2 + v3;
  const int tsum = s3;
  const int lane = t & 63;
  int incl = tsum;
  #pragma unroll
  for (int off = 1; off < 64; off <<= 1) {
    int n = __shfl_up(incl, off);
    if (lane >= off) incl += n;
  }
  const int wid = t >> 6;
  if (lane == 63) wsum[wid] = incl;
  __syncthreads();
  int woff = 0;
  for (int w = 0; w < wid; ++w) woff += wsum[w];
  const int texcl = incl - tsum + woff;
  if (i0 + 0 < NN) rowp1[i0 + 0] = texcl + v0;
  if (i0 + 1 < NN) rowp1[i0 + 1] = texcl + s1;
  if (i0 + 2 < NN) rowp1[i0 + 2] = texcl + s2;
  if (i0 + 3 < NN) rowp1[i0 + 3] = texcl + s3;
  if (t == 255) bsum[blockIdx.x] = texcl + tsum;
}

__global__ void scan2_k(int* __restrict__ bsum, int nb) {
  __shared__ int sh[128];
  const int t = threadIdx.x;
  const int v = (t < nb) ? bsum[t] : 0;
  sh[t] = v;
  __syncthreads();
  #pragma unroll
  for (int off = 1; off < 128; off <<= 1) {
    int nv = (t >= off) ? sh[t - off] : 0;
    __syncthreads();
    sh[t] += nv;
    __syncthreads();
  }
  if (t < nb) bsum[t] = sh[t] - v;
}

__global__ void scan3_k(int* __restrict__ rowp, const int* __restrict__ bsum) {
  const int i = blockIdx.x * blockDim.x + threadIdx.x;
  if (i == 0) rowp[0] = 0;
  if (i < NN) rowp[i + 1] += bsum[i >> 10];
}

__global__ void fill_k(const int* __restrict__ src, const int* __restrict__ dst,
                       int* __restrict__ cursor, int* __restrict__ cidx) {
  for (int e = blockIdx.x * blockDim.x + threadIdx.x; e < NE;
       e += gridDim.x * blockDim.x) {
    const int d = dst[e];
    const int pos = atomicAdd(&cursor[d], 1);
    cidx[pos] = src[e];
  }
}

// ---------------------------------------------------------------- W convert
// W[din][dout] f32 -> Wt hi/lo planes [dout][din] bf16 (transposed, split)
struct WConv { const float* src; unsigned short* hi; unsigned short* lo; int dout; };
struct WConv8 { WConv m[8]; };

__global__ void wconv_k(WConv8 a) {
  const WConv w = a.m[blockIdx.x];
  const int n = 128 * w.dout;
  for (int i = threadIdx.x; i < n; i += blockDim.x) {
    const int c = i >> 7, kk = i & 127;  // out idx = c*128 + kk
    const float x = w.src[(size_t)kk * w.dout + c];
    const unsigned short h = f2bf(x);
    w.hi[i] = h;
    w.lo[i] = f2bf(x - bf2f(h));
  }
}

// ---------------------------------------------------------------- GEMM x4 (MFMA)
// O_m = X @ W_m + b_m, K=128, LDS-free: A and B fragments loaded directly
// global -> register in MFMA fragment order. Split-bf16: acc = Xh*Wh + Xl*Wh
// + Xh*Wl, 6 independent accumulator chains for MFMA ILP.
struct GMat { const unsigned short* wh; const unsigned short* wl;
              const float* bias; float* outf; unsigned short* outb; };
struct GArgs { GMat m[4]; };

template <int DOUT, bool PRESPLIT>
__global__ __launch_bounds__(256, 3)
void gemm4_mfma(const float* __restrict__ X,
                const unsigned short* __restrict__ Xh,
                const unsigned short* __restrict__ Xl,
                int nrows, GArgs ga) {
  constexpr int NF = DOUT / 16;
  const int t = threadIdx.x;
  const int w = t >> 6, l = t & 63;
  const int lr = l & 15, lg = l >> 4;
  const int row0 = blockIdx.x * 128;

  // ---- A fragments (this wave's 32 rows), register-resident ----
  bf16x8 ah[2][4], al[2][4];
  #pragma unroll
  for (int mf = 0; mf < 2; ++mf) {
    const int r = row0 + w * 32 + mf * 16 + lr;
    const bool ok = r < nrows;
    if constexpr (!PRESPLIT) {
      const float* xp = &X[(size_t)r * 128];
      #pragma unroll
      for (int ks = 0; ks < 4; ++ks) {
        float f[8];
        if (ok) {
          *(float4*)&f[0] = *(const float4*)&xp[ks * 32 + lg * 8];
          *(float4*)&f[4] = *(const float4*)&xp[ks * 32 + lg * 8 + 4];
        } else {
          #pragma unroll
          for (int j = 0; j < 8; ++j) f[j] = 0.f;
        }
        split8(f, ah[mf][ks], al[mf][ks]);
      }
    } else {
      #pragma unroll
      for (int ks = 0; ks < 4; ++ks) {
        if (ok) {
          ah[mf][ks] = *(const bf16x8*)&Xh[(size_t)r * 128 + ks * 32 + lg * 8];
          al[mf][ks] = *(const bf16x8*)&Xl[(size_t)r * 128 + ks * 32 + lg * 8];
        } else {
          union { bf16x8 v; unsigned short s[8]; } z;
          #pragma unroll
          for (int j = 0; j < 8; ++j) z.s[j] = 0;
          ah[mf][ks] = z.v; al[mf][ks] = z.v;
        }
      }
    }
  }

  #pragma unroll
  for (int m = 0; m < 4; ++m) {
    const GMat gm = ga.m[m];
    for (int nf = 0; nf < NF; ++nf) {
      bf16x8 bh[4], bl[4];
      #pragma unroll
      for (int ks = 0; ks < 4; ++ks) {
        const size_t off = (size_t)(nf * 16 + lr) * 128 + ks * 32 + lg * 8;
        bh[ks] = *(const bf16x8*)&gm.wh[off];
        bl[ks] = *(const bf16x8*)&gm.wl[off];
      }
      f32x4 aHH = {0.f, 0.f, 0.f, 0.f}, aLH = aHH, aHL = aHH;
      f32x4 bHH = aHH, bLH = aHH, bHL = aHH;
      #pragma unroll
      for (int ks = 0; ks < 4; ++ks) {
        aHH = __builtin_amdgcn_mfma_f32_16x16x32_bf16(ah[0][ks], bh[ks], aHH, 0, 0, 0);
        bHH = __builtin_amdgcn_mfma_f32_16x16x32_bf16(ah[1][ks], bh[ks], bHH, 0, 0, 0);
        aLH = __builtin_amdgcn_mfma_f32_16x16x32_bf16(al[0][ks], bh[ks], aLH, 0, 0, 0);
        bLH = __builtin_amdgcn_mfma_f32_16x16x32_bf16(al[1][ks], bh[ks], bLH, 0, 0, 0);
        aHL = __builtin_amdgcn_mfma_f32_16x16x32_bf16(ah[0][ks], bl[ks], aHL, 0, 0, 0);
        bHL = __builtin_amdgcn_mfma_f32_16x16x32_bf16(ah[1][ks], bl[ks], bHL, 0, 0, 0);
      }
      const f32x4 acc0 = (aHH + aLH) + aHL;
      const f32x4 acc1 = (bHH + bLH) + bHL;
      const int col = nf * 16 + lr;
      const float bb = gm.bias[col];
      #pragma unroll
      for (int j = 0; j < 4; ++j) {
        const int r0 = row0 + w * 32 + lg * 4 + j;   // C/D: row=(l>>4)*4+reg
        const int r1 = r0 + 16;
        if (gm.outb) {
          if (r0 < nrows) gm.outb[(size_t)r0 * DOUT + col] = f2bf(acc0[j] + bb);
          if (r1 < nrows) gm.outb[(size_t)r1 * DOUT + col] = f2bf(acc1[j] + bb);
        } else {
          if (r0 < nrows) gm.outf[(size_t)r0 * DOUT + col] = acc0[j] + bb;
          if (r1 < nrows) gm.outf[(size_t)r1 * DOUT + col] = acc1[j] + bb;
        }
      }
    }
  }
}

// ---------------------------------------------------------------- attention
// Layer 1: heads=8, C=16, concat. 8 lanes/node, one head per lane, 2-edge unroll.
__global__ __launch_bounds__(256)
void attn1_k(const unsigned short* __restrict__ q, const unsigned short* __restrict__ k,
             const unsigned short* __restrict__ v, const float* __restrict__ skip,
             const int* __restrict__ rowp, const int* __restrict__ cidx,
             unsigned short* __restrict__ hhi, unsigned short* __restrict__ hlo) {
  const int node = blockIdx.x * 32 + (threadIdx.x >> 3);
  if (node >= NN) return;
  const int cb = (threadIdx.x & 7) * 16;
  float qv[16];
  {
    uint4 q0 = *(const uint4*)&q[(size_t)node * 128 + cb];
    uint4 q1 = *(const uint4*)&q[(size_t)node * 128 + cb + 8];
    unpack8(q0, qv); unpack8(q1, qv + 8);
    #pragma unroll
    for (int c = 0; c < 16; ++c) qv[c] *= 0.25f;  // 1/sqrt(16)
  }
  float s = 0.f, acc[16];
  #pragma unroll
  for (int c = 0; c < 16; ++c) acc[c] = 0.f;
  const int e0 = rowp[node], e1 = rowp[node + 1];
  int e = e0;
  for (; e + 1 < e1; e += 2) {
    const int sa = cidx[e], sb = cidx[e + 1];
    const uint4 ka0 = *(const uint4*)&k[(size_t)sa * 128 + cb];
    const uint4 ka1 = *(const uint4*)&k[(size_t)sa * 128 + cb + 8];
    const uint4 kb0 = *(const uint4*)&k[(size_t)sb * 128 + cb];
    const uint4 kb1 = *(const uint4*)&k[(size_t)sb * 128 + cb + 8];
    const uint4 va0 = *(const uint4*)&v[(size_t)sa * 128 + cb];
    const uint4 va1 = *(const uint4*)&v[(size_t)sa * 128 + cb + 8];
    const uint4 vb0 = *(const uint4*)&v[(size_t)sb * 128 + cb];
    const uint4 vb1 = *(const uint4*)&v[(size_t)sb * 128 + cb + 8];
    float kva[16], kvb[16];
    unpack8(ka0, kva); unpack8(ka1, kva + 8);
    unpack8(kb0, kvb); unpack8(kb1, kvb + 8);
    float da = 0.f, db = 0.f;
    #pragma unroll
    for (int c = 0; c < 16; ++c) { da = fmaf(qv[c], kva[c], da); db = fmaf(qv[c], kvb[c], db); }
    const float pa = __expf(da), pb = __expf(db);
    s += pa + pb;
    float vva[16], vvb[16];
    unpack8(va0, vva); unpack8(va1, vva + 8);
    unpack8(vb0, vvb); unpack8(vb1, vvb + 8);
    #pragma unroll
    for (int c = 0; c < 16; ++c)
      acc[c] = fmaf(pb, vvb[c], fmaf(pa, vva[c], acc[c]));
  }
  if (e < e1) {
    const int sa = cidx[e];
    uint4 k0 = *(const uint4*)&k[(size_t)sa * 128 + cb];
    uint4 k1 = *(const uint4*)&k[(size_t)sa * 128 + cb + 8];
    float kv[16]; unpack8(k0, kv); unpack8(k1, kv + 8);
    float d = 0.f;
    #pragma unroll
    for (int c = 0; c < 16; ++c) d = fmaf(qv[c], kv[c], d);
    const float p = __expf(d);
    s += p;
    uint4 v0 = *(const uint4*)&v[(size_t)sa * 128 + cb];
    uint4 v1 = *(const uint4*)&v[(size_t)sa * 128 + cb + 8];
    float vv[16]; unpack8(v0, vv); unpack8(v1, vv + 8);
    #pragma unroll
    for (int c = 0; c < 16; ++c) acc[c] = fmaf(p, vv[c], acc[c]);
  }
  const float inv = (e1 > e0) ? 1.f / s : 0.f;
  float sk[16];
  {
    const float* sp = &skip[(size_t)node * 128 + cb];
    *(float4*)&sk[0]  = *(const float4*)&sp[0];
    *(float4*)&sk[4]  = *(const float4*)&sp[4];
    *(float4*)&sk[8]  = *(const float4*)&sp[8];
    *(float4*)&sk[12] = *(const float4*)&sp[12];
  }
  unsigned int hw[8], lw[8];
  #pragma unroll
  for (int c2 = 0; c2 < 8; ++c2) {
    const float oa = fmaxf(fmaf(acc[2 * c2], inv, sk[2 * c2]), 0.f);
    const float ob = fmaxf(fmaf(acc[2 * c2 + 1], inv, sk[2 * c2 + 1]), 0.f);
    const unsigned short ha = f2bf(oa), hb = f2bf(ob);
    hw[c2] = (unsigned)ha | ((unsigned)hb << 16);
    lw[c2] = (unsigned)f2bf(oa - bf2f(ha)) | ((unsigned)f2bf(ob - bf2f(hb)) << 16);
  }
  uint4* HH = (uint4*)&hhi[(size_t)node * 128 + cb];
  uint4* LL = (uint4*)&hlo[(size_t)node * 128 + cb];
  HH[0] = make_uint4(hw[0], hw[1], hw[2], hw[3]);
  HH[1] = make_uint4(hw[4], hw[5], hw[6], hw[7]);
  LL[0] = make_uint4(lw[0], lw[1], lw[2], lw[3]);
  LL[1] = make_uint4(lw[4], lw[5], lw[6], lw[7]);
}

// Layer 2: heads=1, C=64. 8 lanes/node, 8 ch/lane, 3x shfl_xor dot, 2-edge unroll.
__global__ __launch_bounds__(256)
void attn2_k(const unsigned short* __restrict__ q, const unsigned short* __restrict__ k,
             const unsigned short* __restrict__ v, const float* __restrict__ skip,
             const int* __restrict__ rowp, const int* __restrict__ cidx,
             float* __restrict__ out) {
  const int node = blockIdx.x * 32 + (threadIdx.x >> 3);
  if (node >= NN) return;
  const int cb = (threadIdx.x & 7) * 8;
  float qv[8];
  {
    uint4 q0 = *(const uint4*)&q[(size_t)node * 64 + cb];
    unpack8(q0, qv);
    #pragma unroll
    for (int c = 0; c < 8; ++c) qv[c] *= 0.125f;  // 1/sqrt(64)
  }
  float s = 0.f, acc[8];
  #pragma unroll
  for (int c = 0; c < 8; ++c) acc[c] = 0.f;
  const int e0 = rowp[node], e1 = rowp[node + 1];
  int e = e0;
  for (; e + 1 < e1; e += 2) {
    const int sa = cidx[e], sb = cidx[e + 1];
    const uint4 ka = *(const uint4*)&k[(size_t)sa * 64 + cb];
    const uint4 kb = *(const uint4*)&k[(size_t)sb * 64 + cb];
    const uint4 va = *(const uint4*)&v[(size_t)sa * 64 + cb];
    const uint4 vb = *(const uint4*)&v[(size_t)sb * 64 + cb];
    float kva[8], kvb[8];
    unpack8(ka, kva); unpack8(kb, kvb);
    float da = 0.f, db = 0.f;
    #pragma unroll
    for (int c = 0; c < 8; ++c) { da = fmaf(qv[c], kva[c], da); db = fmaf(qv[c], kvb[c], db); }
    da += __shfl_xor(da, 1); db += __shfl_xor(db, 1);
    da += __shfl_xor(da, 2); db += __shfl_xor(db, 2);
    da += __shfl_xor(da, 4); db += __shfl_xor(db, 4);
    const float pa = __expf(da), pb = __expf(db);
    s += pa + pb;
    float vva[8], vvb[8];
    unpack8(va, vva); unpack8(vb, vvb);
    #pragma unroll
    for (int c = 0; c < 8; ++c)
      acc[c] = fmaf(pb, vvb[c], fmaf(pa, vva[c], acc[c]));
  }
  if (e < e1) {
    const int sa = cidx[e];
    uint4 kk = *(const uint4*)&k[(size_t)sa * 64 + cb];
    float kv[8]; unpack8(kk, kv);
    float d = 0.f;
    #pragma unroll
    for (int c = 0; c < 8; ++c) d = fmaf(qv[c], kv[c], d);
    d += __shfl_xor(d, 1);
    d += __shfl_xor(d, 2);
    d += __shfl_xor(d, 4);
    const float p = __expf(d);
    s += p;
    uint4 vv4 = *(const uint4*)&v[(size_t)sa * 64 + cb];
    float vv[8]; unpack8(vv4, vv);
    #pragma unroll
    for (int c = 0; c < 8; ++c) acc[c] = fmaf(p, vv[c], acc[c]);
  }
  const float inv = (e1 > e0) ? 1.f / s : 0.f;
  const float* sp = &skip[(size_t)node * 64 + cb];
  float4 o0, o1;
  o0.x = fmaf(acc[0], inv, sp[0]); o0.y = fmaf(acc[1], inv, sp[1]);
  o0.z = fmaf(acc[2], inv, sp[2]); o0.w = fmaf(acc[3], inv, sp[3]);
  o1.x = fmaf(acc[4], inv, sp[4]); o1.y = fmaf(acc[5], inv, sp[5]);
  o1.z = fmaf(acc[6], inv, sp[6]); o1.w = fmaf(acc[7], inv, sp[7]);
  *(float4*)&out[(size_t)node * 64 + cb] = o0;
  *(float4*)&out[(size_t)node * 64 + cb + 4] = o1;
}

// ---------------------------------------------------------------- launch
extern "C" void kernel_launch(void* const* d_in, const int* in_sizes, int n_in,
                              void* d_out, int out_size, void* d_ws, size_t ws_size,
                              hipStream_t stream) {
  const float* x = (const float*)d_in[0];
  const int* ei = (const int*)d_in[1];
  const int* esrc = ei;
  const int* edst = ei + NE;
  const float* Wf[8] = {(const float*)d_in[2],  (const float*)d_in[4],
                        (const float*)d_in[6],  (const float*)d_in[8],
                        (const float*)d_in[10], (const float*)d_in[12],
                        (const float*)d_in[14], (const float*)d_in[16]};
  const float* Bf[8] = {(const float*)d_in[3],  (const float*)d_in[5],
                        (const float*)d_in[7],  (const float*)d_in[9],
                        (const float*)d_in[11], (const float*)d_in[13],
                        (const float*)d_in[15], (const float*)d_in[17]};
  float* out = (float*)d_out;

  char* p = (char*)d_ws;
  auto alloc = [&](size_t b) { char* r = p; p += (b + 255) & ~(size_t)255; return r; };
  unsigned short* q1 = (unsigned short*)alloc((size_t)NN * 128 * 2);
  unsigned short* k1 = (unsigned short*)alloc((size_t)NN * 128 * 2);
  unsigned short* v1 = (unsigned short*)alloc((size_t)NN * 128 * 2);
  float*          sk1 = (float*)alloc((size_t)NN * 128 * 4);
  unsigned short* hh = (unsigned short*)alloc((size_t)NN * 128 * 2);
  unsigned short* hl = (unsigned short*)alloc((size_t)NN * 128 * 2);
  unsigned short* q2 = (unsigned short*)alloc((size_t)NN * 64 * 2);
  unsigned short* k2 = (unsigned short*)alloc((size_t)NN * 64 * 2);
  unsigned short* v2 = (unsigned short*)alloc((size_t)NN * 64 * 2);
  float*          sk2 = (float*)alloc((size_t)NN * 64 * 4);
  unsigned short* wh[8];
  unsigned short* wl[8];
  for (int i = 0; i < 8; ++i) {
    const int dout = (i < 4) ? 128 : 64;
    wh[i] = (unsigned short*)alloc((size_t)128 * dout * 2);
    wl[i] = (unsigned short*)alloc((size_t)128 * dout * 2);
  }
  int* deg = (int*)alloc((size_t)NN * 4);
  int* rowp = (int*)alloc((size_t)(NN + 1) * 4);
  int* bsum = (int*)alloc(128 * 4);
  int* cursor = (int*)alloc((size_t)NN * 4);
  int* cidx = (int*)alloc((size_t)NE * 4);

  // ---- W convert (transpose + hi/lo split) ----
  WConv8 wc;
  for (int i = 0; i < 8; ++i) wc.m[i] = {Wf[i], wh[i], wl[i], (i < 4) ? 128 : 64};
  wconv_k<<<8, 1024, 0, stream>>>(wc);

  // ---- CSR build (by dst) ----
  hipMemsetAsync(deg, 0, NN * sizeof(int), stream);
  hist_k<<<2048, 256, 0, stream>>>(edst, deg);
  scan1_k<<<(NN + 1023) / 1024, 256, 0, stream>>>(deg, rowp + 1, bsum);
  scan2_k<<<1, 128, 0, stream>>>(bsum, (NN + 1023) / 1024);
  scan3_k<<<(NN + 255) / 256, 256, 0, stream>>>(rowp, bsum);
  hipMemcpyAsync(cursor, rowp, NN * sizeof(int), hipMemcpyDeviceToDevice, stream);
  fill_k<<<2048, 256, 0, stream>>>(esrc, edst, cursor, cidx);

  // ---- layer 1 ----
  GArgs g1;
  g1.m[0] = {wh[0], wl[0], Bf[0], nullptr, q1};
  g1.m[1] = {wh[1], wl[1], Bf[1], nullptr, k1};
  g1.m[2] = {wh[2], wl[2], Bf[2], nullptr, v1};
  g1.m[3] = {wh[3], wl[3], Bf[3], sk1, nullptr};
  gemm4_mfma<128, false><<<(NN + 127) / 128, 256, 0, stream>>>(x, nullptr, nullptr, NN, g1);
  attn1_k<<<(NN + 31) / 32, 256, 0, stream>>>(q1, k1, v1, sk1, rowp, cidx, hh, hl);

  // ---- layer 2 ----
  GArgs g2;
  g2.m[0] = {wh[4], wl[4], Bf[4], nullptr, q2};
  g2.m[1] = {wh[5], wl[5], Bf[5], nullptr, k2};
  g2.m[2] = {wh[6], wl[6], Bf[6], nullptr, v2};
  g2.m[3] = {wh[7], wl[7], Bf[7], sk2, nullptr};
  gemm4_mfma<64, true><<<(NN + 127) / 128, 256, 0, stream>>>(nullptr, hh, hl, NN, g2);
  attn2_k<<<(NN + 31) / 32, 256, 0, stream>>>(q2, k2, v2, sk2, rowp, cidx, out);
}

// Round 4
// 579.516 us; speedup vs baseline: 1.5921x; 1.1258x over previous
//
#include <hip/hip_runtime.h>
#include <math.h>

#define NN 100000
#define NE 1600000

typedef __attribute__((ext_vector_type(8))) short bf16x8;
typedef __attribute__((ext_vector_type(4))) float f32x4;

// ---------------------------------------------------------------- bf16 utils
__device__ __forceinline__ unsigned short f2bf(float x) {
  unsigned int u = __float_as_uint(x);
  u += 0x7fffu + ((u >> 16) & 1u);   // RNE
  return (unsigned short)(u >> 16);
}
__device__ __forceinline__ float bf2f(unsigned short b) {
  return __uint_as_float(((unsigned int)b) << 16);
}
__device__ __forceinline__ void unpack8(uint4 u, float* f) {
  f[0] = __uint_as_float(u.x << 16); f[1] = __uint_as_float(u.x & 0xffff0000u);
  f[2] = __uint_as_float(u.y << 16); f[3] = __uint_as_float(u.y & 0xffff0000u);
  f[4] = __uint_as_float(u.z << 16); f[5] = __uint_as_float(u.z & 0xffff0000u);
  f[6] = __uint_as_float(u.w << 16); f[7] = __uint_as_float(u.w & 0xffff0000u);
}
__device__ __forceinline__ void split8(const float* f, bf16x8& h8, bf16x8& l8) {
  union { bf16x8 v; unsigned short s[8]; } H, L;
  #pragma unroll
  for (int j = 0; j < 8; ++j) {
    const unsigned short hh = f2bf(f[j]);
    H.s[j] = hh;
    L.s[j] = f2bf(f[j] - bf2f(hh));
  }
  h8 = H.v; l8 = L.v;
}
__device__ __forceinline__ void gl_lds16(const void* g, void* lds) {
  __builtin_amdgcn_global_load_lds(
      (const __attribute__((address_space(1))) unsigned int*)g,
      (__attribute__((address_space(3))) unsigned int*)lds, 16, 0, 0);
}

// ---------------------------------------------------------------- CSR build
__global__ void hist_k(const int* __restrict__ dst, int* __restrict__ deg) {
  for (int e = blockIdx.x * blockDim.x + threadIdx.x; e < NE;
       e += gridDim.x * blockDim.x)
    atomicAdd(&deg[dst[e]], 1);
}

__global__ __launch_bounds__(256)
void scan1_k(const int* __restrict__ deg, int* __restrict__ rowp1,
             int* __restrict__ bsum) {
  __shared__ int wsum[4];
  const int t = threadIdx.x;
  const int i0 = blockIdx.x * 1024 + t * 4;
  int v0 = (i0 + 0 < NN) ? deg[i0 + 0] : 0;
  int v1 = (i0 + 1 < NN) ? deg[i0 + 1] : 0;
  int v2 = (i0 + 2 < NN) ? deg[i0 + 2] : 0;
  int v3 = (i0 + 3 < NN) ? deg[i0 + 3] : 0;
  const int s1 = v0 + v1, s2 = s1 + v2, s3 = s2 + v3;
  const int tsum = s3;
  const int lane = t & 63;
  int incl = tsum;
  #pragma unroll
  for (int off = 1; off < 64; off <<= 1) {
    int n = __shfl_up(incl, off);
    if (lane >= off) incl += n;
  }
  const int wid = t >> 6;
  if (lane == 63) wsum[wid] = incl;
  __syncthreads();
  int woff = 0;
  for (int w = 0; w < wid; ++w) woff += wsum[w];
  const int texcl = incl - tsum + woff;
  if (i0 + 0 < NN) rowp1[i0 + 0] = texcl + v0;
  if (i0 + 1 < NN) rowp1[i0 + 1] = texcl + s1;
  if (i0 + 2 < NN) rowp1[i0 + 2] = texcl + s2;
  if (i0 + 3 < NN) rowp1[i0 + 3] = texcl + s3;
  if (t == 255) bsum[blockIdx.x] = texcl + tsum;
}

__global__ void scan2_k(int* __restrict__ bsum, int nb) {
  __shared__ int sh[128];
  const int t = threadIdx.x;
  const int v = (t < nb) ? bsum[t] : 0;
  sh[t] = v;
  __syncthreads();
  #pragma unroll
  for (int off = 1; off < 128; off <<= 1) {
    int nv = (t >= off) ? sh[t - off] : 0;
    __syncthreads();
    sh[t] += nv;
    __syncthreads();
  }
  if (t < nb) bsum[t] = sh[t] - v;
}

__global__ void scan3_k(int* __restrict__ rowp, const int* __restrict__ bsum) {
  const int i = blockIdx.x * blockDim.x + threadIdx.x;
  if (i == 0) rowp[0] = 0;
  if (i < NN) rowp[i + 1] += bsum[i >> 10];
}

__global__ void fill_k(const int* __restrict__ src, const int* __restrict__ dst,
                       int* __restrict__ cursor, int* __restrict__ cidx) {
  for (int e = blockIdx.x * blockDim.x + threadIdx.x; e < NE;
       e += gridDim.x * blockDim.x) {
    const int d = dst[e];
    const int pos = atomicAdd(&cursor[d], 1);
    cidx[pos] = src[e];
  }
}

// ---------------------------------------------------------------- W convert
// W[din][dout] f32 -> Wt hi/lo planes [dout][din] bf16 (transposed, split)
struct WConv { const float* src; unsigned short* hi; unsigned short* lo; int dout; };
struct WConv8 { WConv m[8]; };

__global__ void wconv_k(WConv8 a) {
  const WConv w = a.m[blockIdx.x];
  const int n = 128 * w.dout;
  for (int i = threadIdx.x; i < n; i += blockDim.x) {
    const int c = i >> 7, kk = i & 127;  // out idx = c*128 + kk
    const float x = w.src[(size_t)kk * w.dout + c];
    const unsigned short h = f2bf(x);
    w.hi[i] = h;
    w.lo[i] = f2bf(x - bf2f(h));
  }
}

// ---------------------------------------------------------------- GEMM x4 (MFMA)
// O_m = X @ W_m + b_m, K=128. A (hi/lo) register-resident per wave; B staged
// in 16 KB LDS chunks (one (matrix, 64-col group, plane)) via global_load_lds,
// double-buffered. XOR swizzle ((row&7)<<4) on LDS bytes: linear dest +
// inverse-swizzled global source, same XOR on ds_read (rule #21).
// acc = Xh*Wh + Xl*Wh + Xh*Wl, 8 independent chains (4 nf x 2 rowfrag).
struct GMat { const unsigned short* wh; const unsigned short* wl;
              const float* bias; float* outf; unsigned short* outb; };
struct GArgs { GMat m[4]; };

template <int DOUT, bool PRESPLIT>
__global__ __launch_bounds__(256, 3)
void gemm4_mfma(const float* __restrict__ X,
                const unsigned short* __restrict__ Xh,
                const unsigned short* __restrict__ Xl,
                int nrows, GArgs ga) {
  constexpr int NCG = DOUT / 64;       // 64-col groups per matrix
  constexpr int NS = 4 * NCG * 2;      // stages: matrix x colgroup x plane
  __shared__ __align__(16) unsigned short Bs[2][8192];  // 2 x 16 KB
  const int t = threadIdx.x;
  const int w = t >> 6, l = t & 63;
  const int lr = l & 15, lg = l >> 4;
  const int row0 = blockIdx.x * 128;

  // ---- A fragments (this wave's 32 rows), hi/lo, register-resident ----
  bf16x8 ah[2][4], al[2][4];
  #pragma unroll
  for (int rf = 0; rf < 2; ++rf) {
    const int r = row0 + w * 32 + rf * 16 + lr;
    const bool ok = r < nrows;
    if constexpr (!PRESPLIT) {
      const float* xp = &X[(size_t)r * 128];
      #pragma unroll
      for (int ks = 0; ks < 4; ++ks) {
        float f[8];
        if (ok) {
          *(float4*)&f[0] = *(const float4*)&xp[ks * 32 + lg * 8];
          *(float4*)&f[4] = *(const float4*)&xp[ks * 32 + lg * 8 + 4];
        } else {
          #pragma unroll
          for (int j = 0; j < 8; ++j) f[j] = 0.f;
        }
        split8(f, ah[rf][ks], al[rf][ks]);
      }
    } else {
      #pragma unroll
      for (int ks = 0; ks < 4; ++ks) {
        if (ok) {
          ah[rf][ks] = *(const bf16x8*)&Xh[(size_t)r * 128 + ks * 32 + lg * 8];
          al[rf][ks] = *(const bf16x8*)&Xl[(size_t)r * 128 + ks * 32 + lg * 8];
        } else {
          union { bf16x8 v; unsigned short s[8]; } z;
          #pragma unroll
          for (int j = 0; j < 8; ++j) z.s[j] = 0;
          ah[rf][ks] = z.v; al[rf][ks] = z.v;
        }
      }
    }
  }

  // ---- B stage helper: chunk s -> buf ----
  auto stage = [&](int buf, int s) {
    const int m = s / (NCG * 2);
    const int rem = s - m * (NCG * 2);
    const int cg = rem >> 1, pl = rem & 1;
    const char* gb = (const char*)((pl ? ga.m[m].wl : ga.m[m].wh) + cg * 64 * 128);
    char* lb = (char*)&Bs[buf][0];
    #pragma unroll
    for (int i = 0; i < 4; ++i) {
      const int seg = (w * 4 + i) << 10;           // 1 KB per wave-iter
      const int o = seg + l * 16;                  // linear LDS dest offset
      const int osw = o ^ (((o >> 8) & 7) << 4);   // inverse-swizzled source
      gl_lds16(gb + osw, lb + seg);
    }
  };

  f32x4 acc[4][2];
  stage(0, 0);
  __syncthreads();
  int cur = 0;
  const int sw = (lr & 7) << 4;
  for (int s = 0; s < NS; ++s) {
    if (s + 1 < NS) stage(cur ^ 1, s + 1);
    const int m = s / (NCG * 2);
    const int rem = s - m * (NCG * 2);
    const int cg = rem >> 1, pl = rem & 1;
    const char* lbase = (const char*)&Bs[cur][0];
    if (pl == 0) {
      // hi plane: acc = Ah*Bh + Al*Bh
      #pragma unroll
      for (int nf = 0; nf < 4; ++nf) {
        const char* lp = lbase + nf * 4096 + lr * 256;
        bf16x8 bq[4];
        #pragma unroll
        for (int ks = 0; ks < 4; ++ks)
          bq[ks] = *(const bf16x8*)(lp + (((ks * 64 + lg * 16) ^ sw)));
        f32x4 a0 = {0.f, 0.f, 0.f, 0.f}, a1 = a0;
        #pragma unroll
        for (int ks = 0; ks < 4; ++ks) {
          a0 = __builtin_amdgcn_mfma_f32_16x16x32_bf16(ah[0][ks], bq[ks], a0, 0, 0, 0);
          a1 = __builtin_amdgcn_mfma_f32_16x16x32_bf16(ah[1][ks], bq[ks], a1, 0, 0, 0);
        }
        #pragma unroll
        for (int ks = 0; ks < 4; ++ks) {
          a0 = __builtin_amdgcn_mfma_f32_16x16x32_bf16(al[0][ks], bq[ks], a0, 0, 0, 0);
          a1 = __builtin_amdgcn_mfma_f32_16x16x32_bf16(al[1][ks], bq[ks], a1, 0, 0, 0);
        }
        acc[nf][0] = a0; acc[nf][1] = a1;
      }
    } else {
      // lo plane: acc += Ah*Bl, then epilogue for (m, cg)
      const GMat gm = ga.m[m];
      #pragma unroll
      for (int nf = 0; nf < 4; ++nf) {
        const char* lp = lbase + nf * 4096 + lr * 256;
        bf16x8 bq[4];
        #pragma unroll
        for (int ks = 0; ks < 4; ++ks)
          bq[ks] = *(const bf16x8*)(lp + (((ks * 64 + lg * 16) ^ sw)));
        f32x4 a0 = acc[nf][0], a1 = acc[nf][1];
        #pragma unroll
        for (int ks = 0; ks < 4; ++ks) {
          a0 = __builtin_amdgcn_mfma_f32_16x16x32_bf16(ah[0][ks], bq[ks], a0, 0, 0, 0);
          a1 = __builtin_amdgcn_mfma_f32_16x16x32_bf16(ah[1][ks], bq[ks], a1, 0, 0, 0);
        }
        const int col = cg * 64 + nf * 16 + lr;
        const float bb = gm.bias[col];
        #pragma unroll
        for (int j = 0; j < 4; ++j) {
          const int r0 = row0 + w * 32 + lg * 4 + j;   // C/D: row=(l>>4)*4+reg
          const int r1 = r0 + 16;
          if (gm.outb) {
            if (r0 < nrows) gm.outb[(size_t)r0 * DOUT + col] = f2bf(a0[j] + bb);
            if (r1 < nrows) gm.outb[(size_t)r1 * DOUT + col] = f2bf(a1[j] + bb);
          } else {
            if (r0 < nrows) gm.outf[(size_t)r0 * DOUT + col] = a0[j] + bb;
            if (r1 < nrows) gm.outf[(size_t)r1 * DOUT + col] = a1[j] + bb;
          }
        }
      }
    }
    __syncthreads();   // drains prefetch (vmcnt) + protects LDS reuse
    cur ^= 1;
  }
}

// ---------------------------------------------------------------- attention
// Layer 1: heads=8, C=16, concat. 8 lanes/node, one head per lane, 2-edge unroll.
__global__ __launch_bounds__(256)
void attn1_k(const unsigned short* __restrict__ q, const unsigned short* __restrict__ k,
             const unsigned short* __restrict__ v, const float* __restrict__ skip,
             const int* __restrict__ rowp, const int* __restrict__ cidx,
             unsigned short* __restrict__ hhi, unsigned short* __restrict__ hlo) {
  const int node = blockIdx.x * 32 + (threadIdx.x >> 3);
  if (node >= NN) return;
  const int cb = (threadIdx.x & 7) * 16;
  float qv[16];
  {
    uint4 q0 = *(const uint4*)&q[(size_t)node * 128 + cb];
    uint4 q1 = *(const uint4*)&q[(size_t)node * 128 + cb + 8];
    unpack8(q0, qv); unpack8(q1, qv + 8);
    #pragma unroll
    for (int c = 0; c < 16; ++c) qv[c] *= 0.25f;  // 1/sqrt(16)
  }
  float s = 0.f, acc[16];
  #pragma unroll
  for (int c = 0; c < 16; ++c) acc[c] = 0.f;
  const int e0 = rowp[node], e1 = rowp[node + 1];
  int e = e0;
  for (; e + 1 < e1; e += 2) {
    const int sa = cidx[e], sb = cidx[e + 1];
    const uint4 ka0 = *(const uint4*)&k[(size_t)sa * 128 + cb];
    const uint4 ka1 = *(const uint4*)&k[(size_t)sa * 128 + cb + 8];
    const uint4 kb0 = *(const uint4*)&k[(size_t)sb * 128 + cb];
    const uint4 kb1 = *(const uint4*)&k[(size_t)sb * 128 + cb + 8];
    const uint4 va0 = *(const uint4*)&v[(size_t)sa * 128 + cb];
    const uint4 va1 = *(const uint4*)&v[(size_t)sa * 128 + cb + 8];
    const uint4 vb0 = *(const uint4*)&v[(size_t)sb * 128 + cb];
    const uint4 vb1 = *(const uint4*)&v[(size_t)sb * 128 + cb + 8];
    float kva[16], kvb[16];
    unpack8(ka0, kva); unpack8(ka1, kva + 8);
    unpack8(kb0, kvb); unpack8(kb1, kvb + 8);
    float da = 0.f, db = 0.f;
    #pragma unroll
    for (int c = 0; c < 16; ++c) { da = fmaf(qv[c], kva[c], da); db = fmaf(qv[c], kvb[c], db); }
    const float pa = __expf(da), pb = __expf(db);
    s += pa + pb;
    float vva[16], vvb[16];
    unpack8(va0, vva); unpack8(va1, vva + 8);
    unpack8(vb0, vvb); unpack8(vb1, vvb + 8);
    #pragma unroll
    for (int c = 0; c < 16; ++c)
      acc[c] = fmaf(pb, vvb[c], fmaf(pa, vva[c], acc[c]));
  }
  if (e < e1) {
    const int sa = cidx[e];
    uint4 k0 = *(const uint4*)&k[(size_t)sa * 128 + cb];
    uint4 k1 = *(const uint4*)&k[(size_t)sa * 128 + cb + 8];
    float kv[16]; unpack8(k0, kv); unpack8(k1, kv + 8);
    float d = 0.f;
    #pragma unroll
    for (int c = 0; c < 16; ++c) d = fmaf(qv[c], kv[c], d);
    const float p = __expf(d);
    s += p;
    uint4 v0 = *(const uint4*)&v[(size_t)sa * 128 + cb];
    uint4 v1 = *(const uint4*)&v[(size_t)sa * 128 + cb + 8];
    float vv[16]; unpack8(v0, vv); unpack8(v1, vv + 8);
    #pragma unroll
    for (int c = 0; c < 16; ++c) acc[c] = fmaf(p, vv[c], acc[c]);
  }
  const float inv = (e1 > e0) ? 1.f / s : 0.f;
  float sk[16];
  {
    const float* sp = &skip[(size_t)node * 128 + cb];
    *(float4*)&sk[0]  = *(const float4*)&sp[0];
    *(float4*)&sk[4]  = *(const float4*)&sp[4];
    *(float4*)&sk[8]  = *(const float4*)&sp[8];
    *(float4*)&sk[12] = *(const float4*)&sp[12];
  }
  unsigned int hw[8], lw[8];
  #pragma unroll
  for (int c2 = 0; c2 < 8; ++c2) {
    const float oa = fmaxf(fmaf(acc[2 * c2], inv, sk[2 * c2]), 0.f);
    const float ob = fmaxf(fmaf(acc[2 * c2 + 1], inv, sk[2 * c2 + 1]), 0.f);
    const unsigned short ha = f2bf(oa), hb = f2bf(ob);
    hw[c2] = (unsigned)ha | ((unsigned)hb << 16);
    lw[c2] = (unsigned)f2bf(oa - bf2f(ha)) | ((unsigned)f2bf(ob - bf2f(hb)) << 16);
  }
  uint4* HH = (uint4*)&hhi[(size_t)node * 128 + cb];
  uint4* LL = (uint4*)&hlo[(size_t)node * 128 + cb];
  HH[0] = make_uint4(hw[0], hw[1], hw[2], hw[3]);
  HH[1] = make_uint4(hw[4], hw[5], hw[6], hw[7]);
  LL[0] = make_uint4(lw[0], lw[1], lw[2], lw[3]);
  LL[1] = make_uint4(lw[4], lw[5], lw[6], lw[7]);
}

// Layer 2: heads=1, C=64. 8 lanes/node, 8 ch/lane, 3x shfl_xor dot, 2-edge unroll.
__global__ __launch_bounds__(256)
void attn2_k(const unsigned short* __restrict__ q, const unsigned short* __restrict__ k,
             const unsigned short* __restrict__ v, const float* __restrict__ skip,
             const int* __restrict__ rowp, const int* __restrict__ cidx,
             float* __restrict__ out) {
  const int node = blockIdx.x * 32 + (threadIdx.x >> 3);
  if (node >= NN) return;
  const int cb = (threadIdx.x & 7) * 8;
  float qv[8];
  {
    uint4 q0 = *(const uint4*)&q[(size_t)node * 64 + cb];
    unpack8(q0, qv);
    #pragma unroll
    for (int c = 0; c < 8; ++c) qv[c] *= 0.125f;  // 1/sqrt(64)
  }
  float s = 0.f, acc[8];
  #pragma unroll
  for (int c = 0; c < 8; ++c) acc[c] = 0.f;
  const int e0 = rowp[node], e1 = rowp[node + 1];
  int e = e0;
  for (; e + 1 < e1; e += 2) {
    const int sa = cidx[e], sb = cidx[e + 1];
    const uint4 ka = *(const uint4*)&k[(size_t)sa * 64 + cb];
    const uint4 kb = *(const uint4*)&k[(size_t)sb * 64 + cb];
    const uint4 va = *(const uint4*)&v[(size_t)sa * 64 + cb];
    const uint4 vb = *(const uint4*)&v[(size_t)sb * 64 + cb];
    float kva[8], kvb[8];
    unpack8(ka, kva); unpack8(kb, kvb);
    float da = 0.f, db = 0.f;
    #pragma unroll
    for (int c = 0; c < 8; ++c) { da = fmaf(qv[c], kva[c], da); db = fmaf(qv[c], kvb[c], db); }
    da += __shfl_xor(da, 1); db += __shfl_xor(db, 1);
    da += __shfl_xor(da, 2); db += __shfl_xor(db, 2);
    da += __shfl_xor(da, 4); db += __shfl_xor(db, 4);
    const float pa = __expf(da), pb = __expf(db);
    s += pa + pb;
    float vva[8], vvb[8];
    unpack8(va, vva); unpack8(vb, vvb);
    #pragma unroll
    for (int c = 0; c < 8; ++c)
      acc[c] = fmaf(pb, vvb[c], fmaf(pa, vva[c], acc[c]));
  }
  if (e < e1) {
    const int sa = cidx[e];
    uint4 kk = *(const uint4*)&k[(size_t)sa * 64 + cb];
    float kv[8]; unpack8(kk, kv);
    float d = 0.f;
    #pragma unroll
    for (int c = 0; c < 8; ++c) d = fmaf(qv[c], kv[c], d);
    d += __shfl_xor(d, 1);
    d += __shfl_xor(d, 2);
    d += __shfl_xor(d, 4);
    const float p = __expf(d);
    s += p;
    uint4 vv4 = *(const uint4*)&v[(size_t)sa * 64 + cb];
    float vv[8]; unpack8(vv4, vv);
    #pragma unroll
    for (int c = 0; c < 8; ++c) acc[c] = fmaf(p, vv[c], acc[c]);
  }
  const float inv = (e1 > e0) ? 1.f / s : 0.f;
  const float* sp = &skip[(size_t)node * 64 + cb];
  float4 o0, o1;
  o0.x = fmaf(acc[0], inv, sp[0]); o0.y = fmaf(acc[1], inv, sp[1]);
  o0.z = fmaf(acc[2], inv, sp[2]); o0.w = fmaf(acc[3], inv, sp[3]);
  o1.x = fmaf(acc[4], inv, sp[4]); o1.y = fmaf(acc[5], inv, sp[5]);
  o1.z = fmaf(acc[6], inv, sp[6]); o1.w = fmaf(acc[7], inv, sp[7]);
  *(float4*)&out[(size_t)node * 64 + cb] = o0;
  *(float4*)&out[(size_t)node * 64 + cb + 4] = o1;
}

// ---------------------------------------------------------------- launch
extern "C" void kernel_launch(void* const* d_in, const int* in_sizes, int n_in,
                              void* d_out, int out_size, void* d_ws, size_t ws_size,
                              hipStream_t stream) {
  const float* x = (const float*)d_in[0];
  const int* ei = (const int*)d_in[1];
  const int* esrc = ei;
  const int* edst = ei + NE;
  const float* Wf[8] = {(const float*)d_in[2],  (const float*)d_in[4],
                        (const float*)d_in[6],  (const float*)d_in[8],
                        (const float*)d_in[10], (const float*)d_in[12],
                        (const float*)d_in[14], (const float*)d_in[16]};
  const float* Bf[8] = {(const float*)d_in[3],  (const float*)d_in[5],
                        (const float*)d_in[7],  (const float*)d_in[9],
                        (const float*)d_in[11], (const float*)d_in[13],
                        (const float*)d_in[15], (const float*)d_in[17]};
  float* out = (float*)d_out;

  char* p = (char*)d_ws;
  auto alloc = [&](size_t b) { char* r = p; p += (b + 255) & ~(size_t)255; return r; };
  unsigned short* q1 = (unsigned short*)alloc((size_t)NN * 128 * 2);
  unsigned short* k1 = (unsigned short*)alloc((size_t)NN * 128 * 2);
  unsigned short* v1 = (unsigned short*)alloc((size_t)NN * 128 * 2);
  float*          sk1 = (float*)alloc((size_t)NN * 128 * 4);
  unsigned short* hh = (unsigned short*)alloc((size_t)NN * 128 * 2);
  unsigned short* hl = (unsigned short*)alloc((size_t)NN * 128 * 2);
  unsigned short* q2 = (unsigned short*)alloc((size_t)NN * 64 * 2);
  unsigned short* k2 = (unsigned short*)alloc((size_t)NN * 64 * 2);
  unsigned short* v2 = (unsigned short*)alloc((size_t)NN * 64 * 2);
  float*          sk2 = (float*)alloc((size_t)NN * 64 * 4);
  unsigned short* wh[8];
  unsigned short* wl[8];
  for (int i = 0; i < 8; ++i) {
    const int dout = (i < 4) ? 128 : 64;
    wh[i] = (unsigned short*)alloc((size_t)128 * dout * 2);
    wl[i] = (unsigned short*)alloc((size_t)128 * dout * 2);
  }
  int* deg = (int*)alloc((size_t)NN * 4);
  int* rowp = (int*)alloc((size_t)(NN + 1) * 4);
  int* bsum = (int*)alloc(128 * 4);
  int* cursor = (int*)alloc((size_t)NN * 4);
  int* cidx = (int*)alloc((size_t)NE * 4);

  // ---- W convert (transpose + hi/lo split) ----
  WConv8 wc;
  for (int i = 0; i < 8; ++i) wc.m[i] = {Wf[i], wh[i], wl[i], (i < 4) ? 128 : 64};
  wconv_k<<<8, 1024, 0, stream>>>(wc);

  // ---- CSR build (by dst) ----
  hipMemsetAsync(deg, 0, NN * sizeof(int), stream);
  hist_k<<<2048, 256, 0, stream>>>(edst, deg);
  scan1_k<<<(NN + 1023) / 1024, 256, 0, stream>>>(deg, rowp + 1, bsum);
  scan2_k<<<1, 128, 0, stream>>>(bsum, (NN + 1023) / 1024);
  scan3_k<<<(NN + 255) / 256, 256, 0, stream>>>(rowp, bsum);
  hipMemcpyAsync(cursor, rowp, NN * sizeof(int), hipMemcpyDeviceToDevice, stream);
  fill_k<<<2048, 256, 0, stream>>>(esrc, edst, cursor, cidx);

  // ---- layer 1 ----
  GArgs g1;
  g1.m[0] = {wh[0], wl[0], Bf[0], nullptr, q1};
  g1.m[1] = {wh[1], wl[1], Bf[1], nullptr, k1};
  g1.m[2] = {wh[2], wl[2], Bf[2], nullptr, v1};
  g1.m[3] = {wh[3], wl[3], Bf[3], sk1, nullptr};
  gemm4_mfma<128, false><<<(NN + 127) / 128, 256, 0, stream>>>(x, nullptr, nullptr, NN, g1);
  attn1_k<<<(NN + 31) / 32, 256, 0, stream>>>(q1, k1, v1, sk1, rowp, cidx, hh, hl);

  // ---- layer 2 ----
  GArgs g2;
  g2.m[0] = {wh[4], wl[4], Bf[4], nullptr, q2};
  g2.m[1] = {wh[5], wl[5], Bf[5], nullptr, k2};
  g2.m[2] = {wh[6], wl[6], Bf[6], nullptr, v2};
  g2.m[3] = {wh[7], wl[7], Bf[7], sk2, nullptr};
  gemm4_mfma<64, true><<<(NN + 127) / 128, 256, 0, stream>>>(nullptr, hh, hl, NN, g2);
  attn2_k<<<(NN + 31) / 32, 256, 0, stream>>>(q2, k2, v2, sk2, rowp, cidx, out);
}